// Round 4
// baseline (474.714 us; speedup 1.0000x reference)
//
#include <hip/hip_runtime.h>

// B=8 S=512 D=768 H=256 C=32, G==H
// out[b,s,e,c] = biaff + lin, 8*512*512*32 fp32
//
// Fusion: out[bs,e,c] = sum_g He[b,e,g]*(T[bs,c,g] + W_e[c,g]) + linS[bs,c]+W_b[c]
//   -> W_e folded into T (K3 acc-init), W_b folded into linS (K2), linE removed.
// Operand-swapped MFMAs in K3/K4 put c/g on the register axis (row=q*4+r):
//   K3 stores 8B, K4 stores float4 (16B), acc pre-init = linS'.
// R2: K4: 2 bs/wave, K3: 4 s-tiles/wave; 32 MFMA per 8 streamed loads,
//   ping-pong prefetch of the streamed operand.  (R3's launch-fusion +
//   K1-swizzle bundle regressed +7us -> fully reverted here.)
// R4: s_setprio(1) around MFMA clusters in K3/K4 (independent-wave regime).

typedef __bf16 bf16x8 __attribute__((ext_vector_type(8)));
typedef float f32x4 __attribute__((ext_vector_type(4)));
typedef unsigned int u32x4 __attribute__((ext_vector_type(4)));
typedef unsigned int u32x2 __attribute__((ext_vector_type(2)));

union BF8 { unsigned short s[8]; unsigned int u[4]; bf16x8 v; };

__device__ __forceinline__ unsigned short f2bf(float f) {
    unsigned u = __builtin_bit_cast(unsigned, f);
    u += 0x7fffu + ((u >> 16) & 1u);
    return (unsigned short)(u >> 16);
}
__device__ __forceinline__ float bf2f(unsigned short s) {
    unsigned u = ((unsigned)s) << 16;
    return __builtin_bit_cast(float, u);
}
__device__ __forceinline__ bf16x8 load_bf8(const unsigned short* p) {
    return __builtin_bit_cast(bf16x8, *reinterpret_cast<const uint4*>(p));
}
__device__ __forceinline__ ushort4 pack4(float4 v) {
    ushort4 r;
    r.x = f2bf(v.x); r.y = f2bf(v.y); r.z = f2bf(v.z); r.w = f2bf(v.w);
    return r;
}

// ---------------- KP: fp32 -> bf16 pre-convert: seqb, Wcat --------------
__global__ __launch_bounds__(256) void kp_conv(
    const float* __restrict__ seq, const float* __restrict__ Ws_w,
    const float* __restrict__ We_w, unsigned short* __restrict__ seqb,
    unsigned short* __restrict__ Wcat) {
    int i = blockIdx.x * 256 + threadIdx.x;  // < 884736
    if (i < 786432) {
        float4 v = ((const float4*)seq)[i];
        ((ushort4*)seqb)[i] = pack4(v);
    } else {
        int j = i - 786432;  // 0..98303
        float4 v = (j < 49152) ? ((const float4*)Ws_w)[j]
                               : ((const float4*)We_w)[j - 49152];
        ((ushort4*)Wcat)[j] = pack4(v);
    }
}

// ---------------- K0: Ut[c*256+g][h] = bf16(U[h][c*256+g]) --------------
__global__ __launch_bounds__(256) void k0_ut(const float* __restrict__ U,
                                             unsigned short* __restrict__ Ut) {
    __shared__ float tile[32][33];
    int tx = threadIdx.x, ty = threadIdx.y;
    int J0 = blockIdx.x * 32, h0 = blockIdx.y * 32;
#pragma unroll
    for (int i = 0; i < 4; i++)
        tile[ty + 8 * i][tx] = U[(h0 + ty + 8 * i) * 8192 + J0 + tx];
    __syncthreads();
#pragma unroll
    for (int i = 0; i < 4; i++)
        Ut[(J0 + ty + 8 * i) * 256 + h0 + tx] = f2bf(tile[tx][ty + 8 * i]);
}

// ---------------- K1: Hs/He = bf16(seqb @ Wcat^T + bias), 32x32/wave ----
__global__ __launch_bounds__(256) void k1_hs_he(
    const unsigned short* __restrict__ seqb, const unsigned short* __restrict__ Wcat,
    const float* __restrict__ Ws_b, const float* __restrict__ We_b,
    unsigned short* __restrict__ Hs, unsigned short* __restrict__ He) {
    int wid = threadIdx.x >> 6, lane = threadIdx.x & 63;
    int t = lane & 15, q = lane >> 4;
    int wave_id = blockIdx.x * 4 + wid;  // 0..2047
    int m0 = (wave_id >> 4) * 32;        // 0..4064
    int n0 = (wave_id & 15) * 32;        // 0..480

    const unsigned short* a0 = seqb + (size_t)(m0 + t) * 768;
    const unsigned short* a1 = seqb + (size_t)(m0 + 16 + t) * 768;
    const unsigned short* b0 = Wcat + (size_t)(n0 + t) * 768;
    const unsigned short* b1 = Wcat + (size_t)(n0 + 16 + t) * 768;

    f32x4 acc[2][2];
#pragma unroll
    for (int i = 0; i < 2; i++)
#pragma unroll
        for (int j = 0; j < 2; j++) acc[i][j] = {0.f, 0.f, 0.f, 0.f};

#pragma unroll 4
    for (int kk = 0; kk < 24; kk++) {
        int k = kk * 32 + q * 8;
        bf16x8 af0 = load_bf8(a0 + k);
        bf16x8 af1 = load_bf8(a1 + k);
        bf16x8 bf0 = load_bf8(b0 + k);
        bf16x8 bf1 = load_bf8(b1 + k);
        acc[0][0] = __builtin_amdgcn_mfma_f32_16x16x32_bf16(af0, bf0, acc[0][0], 0, 0, 0);
        acc[0][1] = __builtin_amdgcn_mfma_f32_16x16x32_bf16(af0, bf1, acc[0][1], 0, 0, 0);
        acc[1][0] = __builtin_amdgcn_mfma_f32_16x16x32_bf16(af1, bf0, acc[1][0], 0, 0, 0);
        acc[1][1] = __builtin_amdgcn_mfma_f32_16x16x32_bf16(af1, bf1, acc[1][1], 0, 0, 0);
    }
#pragma unroll
    for (int nt = 0; nt < 2; nt++) {
        int col = n0 + nt * 16 + t;
        float bv;
        unsigned short* dst;
        int c2;
        if (col < 256) { bv = Ws_b[col]; dst = Hs; c2 = col; }
        else           { bv = We_b[col - 256]; dst = He; c2 = col - 256; }
#pragma unroll
        for (int mt = 0; mt < 2; mt++)
#pragma unroll
            for (int r = 0; r < 4; r++) {
                int row = m0 + mt * 16 + q * 4 + r;
                dst[row * 256 + c2] = f2bf(acc[mt][nt][r] + bv);
            }
    }
}

// ---------------- K2: linS'[bs,c] = Hs.W_s^T + W_b  (linE folded away) --
__global__ __launch_bounds__(256) void k2_lin(
    const unsigned short* __restrict__ Hs, const float* __restrict__ W_w,
    const float* __restrict__ W_b, float* __restrict__ linS) {
    int idx = blockIdx.x * 256 + threadIdx.x;  // 0..131071
    int c = idx & 31;
    int bs = idx >> 5;
    const unsigned short* Hrow = Hs + bs * 256;
    const float* Wrow = W_w + c * 512;  // W_s part
    float acc = W_b[c];
#pragma unroll 4
    for (int h8 = 0; h8 < 32; h8++) {
        BF8 hv;
        hv.v = load_bf8(Hrow + h8 * 8);
        float4 w0 = *(const float4*)(Wrow + h8 * 8);
        float4 w1 = *(const float4*)(Wrow + h8 * 8 + 4);
        acc += bf2f(hv.s[0]) * w0.x + bf2f(hv.s[1]) * w0.y + bf2f(hv.s[2]) * w0.z +
               bf2f(hv.s[3]) * w0.w + bf2f(hv.s[4]) * w1.x + bf2f(hv.s[5]) * w1.y +
               bf2f(hv.s[6]) * w1.z + bf2f(hv.s[7]) * w1.w;
    }
    linS[bs * 32 + c] = acc;
}

// ---------------- K3: T[bs][c][g] = bf16( Hs.Ut + W_e[c,g] ) ------------
// Operand-swapped: A=Ut(g rows), B=Hs(s rows) -> D reg axis = g.
// 4 s-tiles/wave (Hs frags resident); Ut streamed ping-pong; 32 MFMA / 8 loads.
// XCD swizzle: n_blk = blockIdx&63 -> XCD = n_blk&7; per-XCD Ut slice 512KB.
__global__ __launch_bounds__(256) void k3_T(
    const unsigned short* __restrict__ Hs, const unsigned short* __restrict__ Ut,
    const float* __restrict__ W_w, unsigned short* __restrict__ T) {
    int wid = threadIdx.x >> 6, lane = threadIdx.x & 63;
    int t = lane & 15, q = lane >> 4;
    int n_blk = blockIdx.x & 63;            // fixed per block
    int mb = (blockIdx.x >> 6) * 4 + wid;   // 0..63
    int c = n_blk >> 1;
    int g0 = (n_blk & 1) * 128;
    int s0 = mb * 64;

    bf16x8 hfr[4][8];  // Hs fragments (B operand), 4 s-tiles resident
#pragma unroll
    for (int mt = 0; mt < 4; mt++) {
        const unsigned short* arow = Hs + (size_t)(s0 + mt * 16 + t) * 256 + q * 8;
#pragma unroll
        for (int kk = 0; kk < 8; kk++) hfr[mt][kk] = load_bf8(arow + kk * 32);
    }

    const unsigned short* gbase = Ut + (size_t)(c * 256 + g0 + t) * 256 + q * 8;
    bf16x8 g_cur[8], g_alt[8];
#pragma unroll
    for (int kk = 0; kk < 8; kk++) g_cur[kk] = load_bf8(gbase + kk * 32);

#define K3_BODY(NT, GC, GN)                                                      \
    {                                                                            \
        const int nt = (NT);                                                     \
        if (nt + 1 < 8) {                                                        \
            const unsigned short* gn = gbase + (size_t)(nt + 1) * 16 * 256;      \
            _Pragma("unroll") for (int kk = 0; kk < 8; kk++)                     \
                GN[kk] = load_bf8(gn + kk * 32);                                 \
        }                                                                        \
        float4 we = *(const float4*)(W_w + c * 512 + 256 + g0 + nt * 16 + q * 4);\
        f32x4 acc0 = {we.x, we.y, we.z, we.w};                                   \
        f32x4 acc1 = acc0, acc2 = acc0, acc3 = acc0;                             \
        __builtin_amdgcn_s_setprio(1);                                           \
        _Pragma("unroll") for (int kk = 0; kk < 8; kk++) {                       \
            acc0 = __builtin_amdgcn_mfma_f32_16x16x32_bf16(GC[kk], hfr[0][kk], acc0, 0, 0, 0); \
            acc1 = __builtin_amdgcn_mfma_f32_16x16x32_bf16(GC[kk], hfr[1][kk], acc1, 0, 0, 0); \
            acc2 = __builtin_amdgcn_mfma_f32_16x16x32_bf16(GC[kk], hfr[2][kk], acc2, 0, 0, 0); \
            acc3 = __builtin_amdgcn_mfma_f32_16x16x32_bf16(GC[kk], hfr[3][kk], acc3, 0, 0, 0); \
        }                                                                        \
        __builtin_amdgcn_s_setprio(0);                                           \
        int gidx = g0 + nt * 16 + q * 4;                                         \
        f32x4 av[4] = {acc0, acc1, acc2, acc3};                                  \
        _Pragma("unroll") for (int m = 0; m < 4; m++) {                          \
            u32x2 p;                                                             \
            p.x = (unsigned)f2bf(av[m][0]) | ((unsigned)f2bf(av[m][1]) << 16);   \
            p.y = (unsigned)f2bf(av[m][2]) | ((unsigned)f2bf(av[m][3]) << 16);   \
            __builtin_nontemporal_store(                                         \
                p, (u32x2*)(T + (size_t)((s0 + m * 16 + t) * 32 + c) * 256 + gidx)); \
        }                                                                        \
    }

#pragma unroll 1
    for (int np = 0; np < 4; np++) {
        K3_BODY(2 * np, g_cur, g_alt)
        K3_BODY(2 * np + 1, g_alt, g_cur)
    }
#undef K3_BODY
}

// ---------------- K4: out[bs][e][c] = T'[bs] . He[b]^T  + linS' ---------
// Operand-swapped: A=T(c rows), B=He(e rows) -> D reg axis = c -> float4 store.
// 2 bs/wave (T frags resident); He streamed ping-pong; 32 MFMA / 8 loads.
// acc pre-init with linS'[bs,c]; out/T nontemporal (keep He hot in L2).
// XCD swizzle: b = blockIdx&7 -> He[b] (256KB) resident per XCD L2.
// NOTE: final prefetch over-reads ~8KB past He[7] into Ut region -- harmless.
__global__ __launch_bounds__(256) void k4_out(
    const unsigned short* __restrict__ T, const unsigned short* __restrict__ He,
    const float* __restrict__ linS, float* __restrict__ out) {
    int wid = threadIdx.x >> 6, lane = threadIdx.x & 63;
    int t = lane & 15, q = lane >> 4;
    int b = blockIdx.x & 7;
    int s0 = (blockIdx.x >> 3) * 8 + wid * 2;  // this wave: s0, s0+1
    int bs0 = b * 512 + s0;

    bf16x8 tfr[2][2][8];  // [bs][ct][kk] T fragments (A operand), resident
#pragma unroll
    for (int u = 0; u < 2; u++)
#pragma unroll
        for (int ct = 0; ct < 2; ct++) {
            const unsigned short* brow =
                T + (size_t)((bs0 + u) * 32 + ct * 16 + t) * 256 + q * 8;
#pragma unroll
            for (int kk = 0; kk < 8; kk++) {
                u32x4 r = __builtin_nontemporal_load((const u32x4*)(brow + kk * 32));
                tfr[u][ct][kk] = __builtin_bit_cast(bf16x8, r);
            }
        }
    f32x4 ls[2][2];
#pragma unroll
    for (int u = 0; u < 2; u++) {
        float4 a = *(const float4*)(linS + (bs0 + u) * 32 + q * 4);
        float4 bv = *(const float4*)(linS + (bs0 + u) * 32 + 16 + q * 4);
        ls[u][0] = {a.x, a.y, a.z, a.w};
        ls[u][1] = {bv.x, bv.y, bv.z, bv.w};
    }

    const unsigned short* Hbase = He + (size_t)(b * 512 + t) * 256 + q * 8;
    bf16x8 a_cur[8], a_alt[8];
#pragma unroll
    for (int kk = 0; kk < 8; kk++) a_cur[kk] = load_bf8(Hbase + kk * 32);

#define K4_BODY(ET, AC, AN)                                                      \
    {                                                                            \
        const int e_t = (ET);                                                    \
        const unsigned short* an = Hbase + (size_t)(e_t + 1) * 16 * 256;         \
        _Pragma("unroll") for (int kk = 0; kk < 8; kk++)                         \
            AN[kk] = load_bf8(an + kk * 32);                                     \
        f32x4 acc00 = ls[0][0], acc01 = ls[0][1];                                \
        f32x4 acc10 = ls[1][0], acc11 = ls[1][1];                                \
        __builtin_amdgcn_s_setprio(1);                                           \
        _Pragma("unroll") for (int kk = 0; kk < 8; kk++) {                       \
            acc00 = __builtin_amdgcn_mfma_f32_16x16x32_bf16(tfr[0][0][kk], AC[kk], acc00, 0, 0, 0); \
            acc01 = __builtin_amdgcn_mfma_f32_16x16x32_bf16(tfr[0][1][kk], AC[kk], acc01, 0, 0, 0); \
            acc10 = __builtin_amdgcn_mfma_f32_16x16x32_bf16(tfr[1][0][kk], AC[kk], acc10, 0, 0, 0); \
            acc11 = __builtin_amdgcn_mfma_f32_16x16x32_bf16(tfr[1][1][kk], AC[kk], acc11, 0, 0, 0); \
        }                                                                        \
        __builtin_amdgcn_s_setprio(0);                                           \
        float* p0 = out + (size_t)bs0 * 16384 + (size_t)(e_t * 16 + t) * 32 + q * 4; \
        __builtin_nontemporal_store(acc00, (f32x4*)p0);                          \
        __builtin_nontemporal_store(acc01, (f32x4*)(p0 + 16));                   \
        float* p1 = p0 + 16384;                                                  \
        __builtin_nontemporal_store(acc10, (f32x4*)p1);                          \
        __builtin_nontemporal_store(acc11, (f32x4*)(p1 + 16));                   \
    }

#pragma unroll 1
    for (int ep = 0; ep < 16; ep++) {
        K4_BODY(2 * ep, a_cur, a_alt)
        K4_BODY(2 * ep + 1, a_alt, a_cur)
    }
#undef K4_BODY
}

extern "C" void kernel_launch(void* const* d_in, const int* in_sizes, int n_in,
                              void* d_out, int out_size, void* d_ws, size_t ws_size,
                              hipStream_t stream) {
    const float* seq  = (const float*)d_in[0];
    const float* U    = (const float*)d_in[1];
    const float* W_w  = (const float*)d_in[2];
    const float* W_b  = (const float*)d_in[3];
    const float* Ws_w = (const float*)d_in[4];
    const float* Ws_b = (const float*)d_in[5];
    const float* We_w = (const float*)d_in[6];
    const float* We_b = (const float*)d_in[7];
    float* out = (float*)d_out;

    char* ws = (char*)d_ws;
    unsigned short* Hs   = (unsigned short*)(ws);                    // 2 MB
    unsigned short* He   = (unsigned short*)(ws + (2ull << 20));     // 2 MB
    unsigned short* Ut   = (unsigned short*)(ws + (4ull << 20));     // 4 MB
    float* linS          = (float*)(ws + (8ull << 20));              // 0.5 MB
    unsigned short* seqb = (unsigned short*)(ws + (9ull << 20));     // 6 MB
    unsigned short* Wcat = (unsigned short*)(ws + (15ull << 20));    // 0.75 MB
    unsigned short* T    = (unsigned short*)(ws + (16ull << 20));    // 64 MB

    kp_conv<<<3456, 256, 0, stream>>>(seq, Ws_w, We_w, seqb, Wcat);
    k0_ut<<<dim3(256, 8), dim3(32, 8), 0, stream>>>(U, Ut);
    k1_hs_he<<<512, 256, 0, stream>>>(seqb, Wcat, Ws_b, We_b, Hs, He);
    k2_lin<<<512, 256, 0, stream>>>(Hs, W_w, W_b, linS);
    k3_T<<<1024, 256, 0, stream>>>(Hs, Ut, W_w, T);
    k4_out<<<512, 256, 0, stream>>>(T, He, linS, out);
}

// Round 6
// 454.912 us; speedup vs baseline: 1.0435x; 1.0435x over previous
//
#include <hip/hip_runtime.h>

// B=8 S=512 D=768 H=256 C=32, G==H
// out[b,s,e,c] = biaff + lin, 8*512*512*32 fp32
//
// Fusion: out[bs,e,c] = sum_g He[b,e,g]*(T[bs,c,g] + W_e[c,g]) + linS[bs,c]+W_b[c]
//   -> W_e folded into T (K3 acc-init), W_b folded into linS (K2), linE removed.
// Operand-swapped MFMAs in K3/K4 put c/g on the register axis (row=q*4+r):
//   K3 stores 8B, K4 stores float4 (16B), acc pre-init = linS'.
// R2 (best, 458.8us): K4: 2 bs/wave, K3: 4 s-tiles/wave; 32 MFMA per 8
//   streamed loads, ping-pong prefetch of the streamed operand.
// R3 (launch fusion + K1 swizzle): +7us -> reverted.
// R4 (setprio around MFMA): +16us (m190-consistent: no wave role-split) -> reverted.
// R5: exact R2 restore -- bench infra failed (container), resubmitting unchanged.
//   dur decomposes as ~340us harness fills (uncontrollable, at HBM ceiling)
//   + ~120us kernels (~12% above composite kernel floor).

typedef __bf16 bf16x8 __attribute__((ext_vector_type(8)));
typedef float f32x4 __attribute__((ext_vector_type(4)));
typedef unsigned int u32x4 __attribute__((ext_vector_type(4)));
typedef unsigned int u32x2 __attribute__((ext_vector_type(2)));

union BF8 { unsigned short s[8]; unsigned int u[4]; bf16x8 v; };

__device__ __forceinline__ unsigned short f2bf(float f) {
    unsigned u = __builtin_bit_cast(unsigned, f);
    u += 0x7fffu + ((u >> 16) & 1u);
    return (unsigned short)(u >> 16);
}
__device__ __forceinline__ float bf2f(unsigned short s) {
    unsigned u = ((unsigned)s) << 16;
    return __builtin_bit_cast(float, u);
}
__device__ __forceinline__ bf16x8 load_bf8(const unsigned short* p) {
    return __builtin_bit_cast(bf16x8, *reinterpret_cast<const uint4*>(p));
}
__device__ __forceinline__ ushort4 pack4(float4 v) {
    ushort4 r;
    r.x = f2bf(v.x); r.y = f2bf(v.y); r.z = f2bf(v.z); r.w = f2bf(v.w);
    return r;
}

// ---------------- KP: fp32 -> bf16 pre-convert: seqb, Wcat --------------
__global__ __launch_bounds__(256) void kp_conv(
    const float* __restrict__ seq, const float* __restrict__ Ws_w,
    const float* __restrict__ We_w, unsigned short* __restrict__ seqb,
    unsigned short* __restrict__ Wcat) {
    int i = blockIdx.x * 256 + threadIdx.x;  // < 884736
    if (i < 786432) {
        float4 v = ((const float4*)seq)[i];
        ((ushort4*)seqb)[i] = pack4(v);
    } else {
        int j = i - 786432;  // 0..98303
        float4 v = (j < 49152) ? ((const float4*)Ws_w)[j]
                               : ((const float4*)We_w)[j - 49152];
        ((ushort4*)Wcat)[j] = pack4(v);
    }
}

// ---------------- K0: Ut[c*256+g][h] = bf16(U[h][c*256+g]) --------------
__global__ __launch_bounds__(256) void k0_ut(const float* __restrict__ U,
                                             unsigned short* __restrict__ Ut) {
    __shared__ float tile[32][33];
    int tx = threadIdx.x, ty = threadIdx.y;
    int J0 = blockIdx.x * 32, h0 = blockIdx.y * 32;
#pragma unroll
    for (int i = 0; i < 4; i++)
        tile[ty + 8 * i][tx] = U[(h0 + ty + 8 * i) * 8192 + J0 + tx];
    __syncthreads();
#pragma unroll
    for (int i = 0; i < 4; i++)
        Ut[(J0 + ty + 8 * i) * 256 + h0 + tx] = f2bf(tile[tx][ty + 8 * i]);
}

// ---------------- K1: Hs/He = bf16(seqb @ Wcat^T + bias), 32x32/wave ----
__global__ __launch_bounds__(256) void k1_hs_he(
    const unsigned short* __restrict__ seqb, const unsigned short* __restrict__ Wcat,
    const float* __restrict__ Ws_b, const float* __restrict__ We_b,
    unsigned short* __restrict__ Hs, unsigned short* __restrict__ He) {
    int wid = threadIdx.x >> 6, lane = threadIdx.x & 63;
    int t = lane & 15, q = lane >> 4;
    int wave_id = blockIdx.x * 4 + wid;  // 0..2047
    int m0 = (wave_id >> 4) * 32;        // 0..4064
    int n0 = (wave_id & 15) * 32;        // 0..480

    const unsigned short* a0 = seqb + (size_t)(m0 + t) * 768;
    const unsigned short* a1 = seqb + (size_t)(m0 + 16 + t) * 768;
    const unsigned short* b0 = Wcat + (size_t)(n0 + t) * 768;
    const unsigned short* b1 = Wcat + (size_t)(n0 + 16 + t) * 768;

    f32x4 acc[2][2];
#pragma unroll
    for (int i = 0; i < 2; i++)
#pragma unroll
        for (int j = 0; j < 2; j++) acc[i][j] = {0.f, 0.f, 0.f, 0.f};

#pragma unroll 4
    for (int kk = 0; kk < 24; kk++) {
        int k = kk * 32 + q * 8;
        bf16x8 af0 = load_bf8(a0 + k);
        bf16x8 af1 = load_bf8(a1 + k);
        bf16x8 bf0 = load_bf8(b0 + k);
        bf16x8 bf1 = load_bf8(b1 + k);
        acc[0][0] = __builtin_amdgcn_mfma_f32_16x16x32_bf16(af0, bf0, acc[0][0], 0, 0, 0);
        acc[0][1] = __builtin_amdgcn_mfma_f32_16x16x32_bf16(af0, bf1, acc[0][1], 0, 0, 0);
        acc[1][0] = __builtin_amdgcn_mfma_f32_16x16x32_bf16(af1, bf0, acc[1][0], 0, 0, 0);
        acc[1][1] = __builtin_amdgcn_mfma_f32_16x16x32_bf16(af1, bf1, acc[1][1], 0, 0, 0);
    }
#pragma unroll
    for (int nt = 0; nt < 2; nt++) {
        int col = n0 + nt * 16 + t;
        float bv;
        unsigned short* dst;
        int c2;
        if (col < 256) { bv = Ws_b[col]; dst = Hs; c2 = col; }
        else           { bv = We_b[col - 256]; dst = He; c2 = col - 256; }
#pragma unroll
        for (int mt = 0; mt < 2; mt++)
#pragma unroll
            for (int r = 0; r < 4; r++) {
                int row = m0 + mt * 16 + q * 4 + r;
                dst[row * 256 + c2] = f2bf(acc[mt][nt][r] + bv);
            }
    }
}

// ---------------- K2: linS'[bs,c] = Hs.W_s^T + W_b  (linE folded away) --
__global__ __launch_bounds__(256) void k2_lin(
    const unsigned short* __restrict__ Hs, const float* __restrict__ W_w,
    const float* __restrict__ W_b, float* __restrict__ linS) {
    int idx = blockIdx.x * 256 + threadIdx.x;  // 0..131071
    int c = idx & 31;
    int bs = idx >> 5;
    const unsigned short* Hrow = Hs + bs * 256;
    const float* Wrow = W_w + c * 512;  // W_s part
    float acc = W_b[c];
#pragma unroll 4
    for (int h8 = 0; h8 < 32; h8++) {
        BF8 hv;
        hv.v = load_bf8(Hrow + h8 * 8);
        float4 w0 = *(const float4*)(Wrow + h8 * 8);
        float4 w1 = *(const float4*)(Wrow + h8 * 8 + 4);
        acc += bf2f(hv.s[0]) * w0.x + bf2f(hv.s[1]) * w0.y + bf2f(hv.s[2]) * w0.z +
               bf2f(hv.s[3]) * w0.w + bf2f(hv.s[4]) * w1.x + bf2f(hv.s[5]) * w1.y +
               bf2f(hv.s[6]) * w1.z + bf2f(hv.s[7]) * w1.w;
    }
    linS[bs * 32 + c] = acc;
}

// ---------------- K3: T[bs][c][g] = bf16( Hs.Ut + W_e[c,g] ) ------------
// Operand-swapped: A=Ut(g rows), B=Hs(s rows) -> D reg axis = g.
// 4 s-tiles/wave (Hs frags resident); Ut streamed ping-pong; 32 MFMA / 8 loads.
// XCD swizzle: n_blk = blockIdx&63 -> XCD = n_blk&7; per-XCD Ut slice 512KB.
__global__ __launch_bounds__(256) void k3_T(
    const unsigned short* __restrict__ Hs, const unsigned short* __restrict__ Ut,
    const float* __restrict__ W_w, unsigned short* __restrict__ T) {
    int wid = threadIdx.x >> 6, lane = threadIdx.x & 63;
    int t = lane & 15, q = lane >> 4;
    int n_blk = blockIdx.x & 63;            // fixed per block
    int mb = (blockIdx.x >> 6) * 4 + wid;   // 0..63
    int c = n_blk >> 1;
    int g0 = (n_blk & 1) * 128;
    int s0 = mb * 64;

    bf16x8 hfr[4][8];  // Hs fragments (B operand), 4 s-tiles resident
#pragma unroll
    for (int mt = 0; mt < 4; mt++) {
        const unsigned short* arow = Hs + (size_t)(s0 + mt * 16 + t) * 256 + q * 8;
#pragma unroll
        for (int kk = 0; kk < 8; kk++) hfr[mt][kk] = load_bf8(arow + kk * 32);
    }

    const unsigned short* gbase = Ut + (size_t)(c * 256 + g0 + t) * 256 + q * 8;
    bf16x8 g_cur[8], g_alt[8];
#pragma unroll
    for (int kk = 0; kk < 8; kk++) g_cur[kk] = load_bf8(gbase + kk * 32);

#define K3_BODY(NT, GC, GN)                                                      \
    {                                                                            \
        const int nt = (NT);                                                     \
        if (nt + 1 < 8) {                                                        \
            const unsigned short* gn = gbase + (size_t)(nt + 1) * 16 * 256;      \
            _Pragma("unroll") for (int kk = 0; kk < 8; kk++)                     \
                GN[kk] = load_bf8(gn + kk * 32);                                 \
        }                                                                        \
        float4 we = *(const float4*)(W_w + c * 512 + 256 + g0 + nt * 16 + q * 4);\
        f32x4 acc0 = {we.x, we.y, we.z, we.w};                                   \
        f32x4 acc1 = acc0, acc2 = acc0, acc3 = acc0;                             \
        _Pragma("unroll") for (int kk = 0; kk < 8; kk++) {                       \
            acc0 = __builtin_amdgcn_mfma_f32_16x16x32_bf16(GC[kk], hfr[0][kk], acc0, 0, 0, 0); \
            acc1 = __builtin_amdgcn_mfma_f32_16x16x32_bf16(GC[kk], hfr[1][kk], acc1, 0, 0, 0); \
            acc2 = __builtin_amdgcn_mfma_f32_16x16x32_bf16(GC[kk], hfr[2][kk], acc2, 0, 0, 0); \
            acc3 = __builtin_amdgcn_mfma_f32_16x16x32_bf16(GC[kk], hfr[3][kk], acc3, 0, 0, 0); \
        }                                                                        \
        int gidx = g0 + nt * 16 + q * 4;                                         \
        f32x4 av[4] = {acc0, acc1, acc2, acc3};                                  \
        _Pragma("unroll") for (int m = 0; m < 4; m++) {                          \
            u32x2 p;                                                             \
            p.x = (unsigned)f2bf(av[m][0]) | ((unsigned)f2bf(av[m][1]) << 16);   \
            p.y = (unsigned)f2bf(av[m][2]) | ((unsigned)f2bf(av[m][3]) << 16);   \
            __builtin_nontemporal_store(                                         \
                p, (u32x2*)(T + (size_t)((s0 + m * 16 + t) * 32 + c) * 256 + gidx)); \
        }                                                                        \
    }

#pragma unroll 1
    for (int np = 0; np < 4; np++) {
        K3_BODY(2 * np, g_cur, g_alt)
        K3_BODY(2 * np + 1, g_alt, g_cur)
    }
#undef K3_BODY
}

// ---------------- K4: out[bs][e][c] = T'[bs] . He[b]^T  + linS' ---------
// Operand-swapped: A=T(c rows), B=He(e rows) -> D reg axis = c -> float4 store.
// 2 bs/wave (T frags resident); He streamed ping-pong; 32 MFMA / 8 loads.
// acc pre-init with linS'[bs,c]; out/T nontemporal (keep He hot in L2).
// XCD swizzle: b = blockIdx&7 -> He[b] (256KB) resident per XCD L2.
// NOTE: final prefetch over-reads ~8KB past He[7] into Ut region -- harmless.
__global__ __launch_bounds__(256) void k4_out(
    const unsigned short* __restrict__ T, const unsigned short* __restrict__ He,
    const float* __restrict__ linS, float* __restrict__ out) {
    int wid = threadIdx.x >> 6, lane = threadIdx.x & 63;
    int t = lane & 15, q = lane >> 4;
    int b = blockIdx.x & 7;
    int s0 = (blockIdx.x >> 3) * 8 + wid * 2;  // this wave: s0, s0+1
    int bs0 = b * 512 + s0;

    bf16x8 tfr[2][2][8];  // [bs][ct][kk] T fragments (A operand), resident
#pragma unroll
    for (int u = 0; u < 2; u++)
#pragma unroll
        for (int ct = 0; ct < 2; ct++) {
            const unsigned short* brow =
                T + (size_t)((bs0 + u) * 32 + ct * 16 + t) * 256 + q * 8;
#pragma unroll
            for (int kk = 0; kk < 8; kk++) {
                u32x4 r = __builtin_nontemporal_load((const u32x4*)(brow + kk * 32));
                tfr[u][ct][kk] = __builtin_bit_cast(bf16x8, r);
            }
        }
    f32x4 ls[2][2];
#pragma unroll
    for (int u = 0; u < 2; u++) {
        float4 a = *(const float4*)(linS + (bs0 + u) * 32 + q * 4);
        float4 bv = *(const float4*)(linS + (bs0 + u) * 32 + 16 + q * 4);
        ls[u][0] = {a.x, a.y, a.z, a.w};
        ls[u][1] = {bv.x, bv.y, bv.z, bv.w};
    }

    const unsigned short* Hbase = He + (size_t)(b * 512 + t) * 256 + q * 8;
    bf16x8 a_cur[8], a_alt[8];
#pragma unroll
    for (int kk = 0; kk < 8; kk++) a_cur[kk] = load_bf8(Hbase + kk * 32);

#define K4_BODY(ET, AC, AN)                                                      \
    {                                                                            \
        const int e_t = (ET);                                                    \
        const unsigned short* an = Hbase + (size_t)(e_t + 1) * 16 * 256;         \
        _Pragma("unroll") for (int kk = 0; kk < 8; kk++)                         \
            AN[kk] = load_bf8(an + kk * 32);                                     \
        f32x4 acc00 = ls[0][0], acc01 = ls[0][1];                                \
        f32x4 acc10 = ls[1][0], acc11 = ls[1][1];                                \
        _Pragma("unroll") for (int kk = 0; kk < 8; kk++) {                       \
            acc00 = __builtin_amdgcn_mfma_f32_16x16x32_bf16(tfr[0][0][kk], AC[kk], acc00, 0, 0, 0); \
            acc01 = __builtin_amdgcn_mfma_f32_16x16x32_bf16(tfr[0][1][kk], AC[kk], acc01, 0, 0, 0); \
            acc10 = __builtin_amdgcn_mfma_f32_16x16x32_bf16(tfr[1][0][kk], AC[kk], acc10, 0, 0, 0); \
            acc11 = __builtin_amdgcn_mfma_f32_16x16x32_bf16(tfr[1][1][kk], AC[kk], acc11, 0, 0, 0); \
        }                                                                        \
        float* p0 = out + (size_t)bs0 * 16384 + (size_t)(e_t * 16 + t) * 32 + q * 4; \
        __builtin_nontemporal_store(acc00, (f32x4*)p0);                          \
        __builtin_nontemporal_store(acc01, (f32x4*)(p0 + 16));                   \
        float* p1 = p0 + 16384;                                                  \
        __builtin_nontemporal_store(acc10, (f32x4*)p1);                          \
        __builtin_nontemporal_store(acc11, (f32x4*)(p1 + 16));                   \
    }

#pragma unroll 1
    for (int ep = 0; ep < 16; ep++) {
        K4_BODY(2 * ep, a_cur, a_alt)
        K4_BODY(2 * ep + 1, a_alt, a_cur)
    }
#undef K4_BODY
}

extern "C" void kernel_launch(void* const* d_in, const int* in_sizes, int n_in,
                              void* d_out, int out_size, void* d_ws, size_t ws_size,
                              hipStream_t stream) {
    const float* seq  = (const float*)d_in[0];
    const float* U    = (const float*)d_in[1];
    const float* W_w  = (const float*)d_in[2];
    const float* W_b  = (const float*)d_in[3];
    const float* Ws_w = (const float*)d_in[4];
    const float* Ws_b = (const float*)d_in[5];
    const float* We_w = (const float*)d_in[6];
    const float* We_b = (const float*)d_in[7];
    float* out = (float*)d_out;

    char* ws = (char*)d_ws;
    unsigned short* Hs   = (unsigned short*)(ws);                    // 2 MB
    unsigned short* He   = (unsigned short*)(ws + (2ull << 20));     // 2 MB
    unsigned short* Ut   = (unsigned short*)(ws + (4ull << 20));     // 4 MB
    float* linS          = (float*)(ws + (8ull << 20));              // 0.5 MB
    unsigned short* seqb = (unsigned short*)(ws + (9ull << 20));     // 6 MB
    unsigned short* Wcat = (unsigned short*)(ws + (15ull << 20));    // 0.75 MB
    unsigned short* T    = (unsigned short*)(ws + (16ull << 20));    // 64 MB

    kp_conv<<<3456, 256, 0, stream>>>(seq, Ws_w, We_w, seqb, Wcat);
    k0_ut<<<dim3(256, 8), dim3(32, 8), 0, stream>>>(U, Ut);
    k1_hs_he<<<512, 256, 0, stream>>>(seqb, Wcat, Ws_b, We_b, Hs, He);
    k2_lin<<<512, 256, 0, stream>>>(Hs, W_w, W_b, linS);
    k3_T<<<1024, 256, 0, stream>>>(Hs, Ut, W_w, T);
    k4_out<<<512, 256, 0, stream>>>(T, He, linS, out);
}